// Round 2
// baseline (123.959 us; speedup 1.0000x reference)
//
#include <hip/hip_runtime.h>
#include <hip/hip_bf16.h>

#define NFFT    512
#define HOPSZ   128
#define FBINS   257
#define TFR     2048
#define NBC     32            // B*C
#define KSTEPS  17            // ceil(514/32)
#define OUTLEN  262016        // (T-1)*HOP
#define SPAD    256           // n_fft/2 (center trim)

typedef __bf16 bf16x8 __attribute__((ext_vector_type(8)));
typedef float  f32x4  __attribute__((ext_vector_type(4)));

static __device__ __forceinline__ float bf2f(unsigned short u) {
    union { unsigned int i; float f; } x; x.i = (unsigned int)u << 16; return x.f;
}

// ---------------------------------------------------------------------------
// Kernel 1: W' in MFMA A-fragment order.
//   Wf[(ks*32 + rt)*64 + lane] = uint4 of 8 bf16, element j:
//     n = rt*16 + (lane&15),  k = ks*32 + (lane>>4)*4 + (j&3) + 16*(j>>2)
//   value = window[n]/512 * inverse-rDFT coeff (cos / -sin interleaved),
//   zero for k >= 514 and for sin terms of f in {0,256}.
// ---------------------------------------------------------------------------
__global__ __launch_bounds__(256) void k_wgen(const float* __restrict__ wnd,
                                              uint4* __restrict__ Wf) {
    const int gid  = blockIdx.x * 256 + threadIdx.x;   // < 17*32*64 = 34816
    const int lane = gid & 63;
    const int rt   = (gid >> 6) & 31;
    const int ks   = gid >> 11;
    const int n    = rt * 16 + (lane & 15);
    const int kb   = ks * 32 + ((lane >> 4) << 2);
    const float wn = wnd[n] * (1.0f / 512.0f);
    union { uint4 u; unsigned short h[8]; } o;
    #pragma unroll
    for (int j = 0; j < 8; ++j) {
        const int k = kb + (j & 3) + 16 * (j >> 2);
        float val = 0.0f;
        if (k < 2 * FBINS) {
            const int f = k >> 1;
            const bool edge = (f == 0) || (f == 256);
            const float cf = edge ? 1.0f : 2.0f;
            const int m = (f * n) & (NFFT - 1);              // exact arg reduction
            const float ang = (float)m * 0.01227184630308513f; // 2*pi/512
            float s, c;
            __sincosf(ang, &s, &c);
            val = (k & 1) ? (edge ? 0.0f : -cf * wn * s) : (cf * wn * c);
        }
        __hip_bfloat16 hb = __float2bfloat16(val);
        o.h[j] = *(unsigned short*)&hb;
    }
    Wf[gid] = o.u;
}

// ---------------------------------------------------------------------------
// Kernel 2: frames = W' @ Xb — NO LDS, NO barriers.
//   1024 blocks x 256 threads (4 waves). Block: rows [wr*128,+128), t-cols
//   [tc*256,+256); wave w: 64 t-cols. acc 8x4 of 16x16x32 frags.
//   A-frags: direct dwordx4 loads from fragment-ordered Wf (L2/L1).
//   B-frags: 4x float2 (re,im of f0+{0,1,8,9}) per frag, fp32->bf16 in-reg,
//            1-step raw-register prefetch (brA/brB ping-pong).
// ---------------------------------------------------------------------------
__global__ __launch_bounds__(256, 2) void k_mm(
    const float* __restrict__ X,
    const uint4* __restrict__ Wf,
    __hip_bfloat16* __restrict__ frames)
{
    const int tid  = threadIdx.x;
    const int lane = tid & 63;
    const int w    = tid >> 6;
    const int wr   = blockIdx.x & 3;          // M-split (128 rows)
    const int tc   = blockIdx.x >> 2;         // 256-col panel
    const int bc   = tc >> 3;                 // batch*channel
    const int t0   = ((tc & 7) << 8) + (w << 6);
    const int q    = lane >> 4;
    const int rlo  = lane & 15;
    const float2* __restrict__ X2 = (const float2*)X + (size_t)bc * FBINS * TFR;

    f32x4  acc[8][4] = {};
    float2 brA[4][4], brB[4][4];
    uint4  a[8];

    auto loadA = [&](int ks) {
        const uint4* wp = Wf + (((size_t)(ks * 32 + wr * 8)) << 6) + lane;
        #pragma unroll
        for (int mi = 0; mi < 8; ++mi) a[mi] = wp[mi << 6];
    };
    auto loadB = [&](int ks, float2 br[4][4]) {
        if (ks >= KSTEPS) return;                      // ping-pong overrun: no-op
        if (ks < KSTEPS - 1) {
            const int f0 = ks * 16 + q * 2;            // max 255 at ks=15,q=3 (+9)... f0+9<=255
            #pragma unroll
            for (int ni = 0; ni < 4; ++ni) {
                const float2* xp = X2 + (size_t)f0 * TFR + (t0 + ni * 16 + rlo);
                br[ni][0] = xp[0];
                br[ni][1] = xp[TFR];
                br[ni][2] = xp[(size_t)8 * TFR];
                br[ni][3] = xp[(size_t)9 * TFR];
            }
        } else {                                       // ks=16: only k=512 (re f=256) live
            #pragma unroll
            for (int ni = 0; ni < 4; ++ni) {
                float2 v = make_float2(0.f, 0.f);
                if (q == 0) v = X2[(size_t)256 * TFR + (t0 + ni * 16 + rlo)];
                br[ni][0] = v;
                br[ni][1] = make_float2(0.f, 0.f);
                br[ni][2] = make_float2(0.f, 0.f);
                br[ni][3] = make_float2(0.f, 0.f);
            }
        }
    };
    auto step = [&](float2 br[4][4]) {
        #pragma unroll
        for (int ni = 0; ni < 4; ++ni) {
            union { unsigned short h[8]; uint4 raw; } pk;
            #pragma unroll
            for (int d = 0; d < 4; ++d) {
                __hip_bfloat16 x = __float2bfloat16(br[ni][d].x);
                __hip_bfloat16 y = __float2bfloat16(br[ni][d].y);
                pk.h[2 * d]     = *(unsigned short*)&x;
                pk.h[2 * d + 1] = *(unsigned short*)&y;
            }
            const bf16x8 bfrag = __builtin_bit_cast(bf16x8, pk.raw);
            #pragma unroll
            for (int mi = 0; mi < 8; ++mi)
                acc[mi][ni] = __builtin_amdgcn_mfma_f32_16x16x32_bf16(
                    __builtin_bit_cast(bf16x8, a[mi]), bfrag, acc[mi][ni], 0, 0, 0);
        }
    };

    loadB(0, brA);
    for (int ks = 0; ks < KSTEPS; ks += 2) {
        loadA(ks);
        loadB(ks + 1, brB);      // prefetch next step's B (raw fp32, no dependent ops)
        step(brA);
        if (ks + 1 < KSTEPS) {
            loadA(ks + 1);
            loadB(ks + 2, brA);
            step(brB);
        }
    }

    // epilogue: C/D layout col(lane&15)=t, row=(lane>>4)*4+reg (m89-verified, R1-passed)
    const int rrow = q << 2;
    unsigned short* fb = (unsigned short*)frames;
    #pragma unroll
    for (int mi = 0; mi < 8; ++mi) {
        const int nbase = wr * 128 + mi * 16 + rrow;
        #pragma unroll
        for (int ni = 0; ni < 4; ++ni) {
            const int t = t0 + ni * 16 + rlo;
            union { ushort4 u; __hip_bfloat16 h[4]; } pk;
            pk.h[0] = __float2bfloat16(acc[mi][ni][0]);
            pk.h[1] = __float2bfloat16(acc[mi][ni][1]);
            pk.h[2] = __float2bfloat16(acc[mi][ni][2]);
            pk.h[3] = __float2bfloat16(acc[mi][ni][3]);
            *(ushort4*)(fb + (((size_t)(bc * TFR + t) << 9) + nbase)) = pk.u;
        }
    }
}

// ---------------------------------------------------------------------------
// Kernel 3: overlap-add + envelope normalize. 4 outputs / thread.
// ---------------------------------------------------------------------------
__global__ __launch_bounds__(256) void k_ola(
    const __hip_bfloat16* __restrict__ frames,
    const float* __restrict__ wnd,
    float* __restrict__ out)
{
    const int bc = blockIdx.y;
    const int o  = (blockIdx.x * 256 + threadIdx.x) * 4;
    if (o >= OUTLEN) return;
    const int s  = o + SPAD;
    const int tb = s >> 7;
    const int nb = s & (HOPSZ - 1);
    const unsigned short* fb = (const unsigned short*)frames + (size_t)bc * TFR * NFFT;
    float y0 = 0.f, y1 = 0.f, y2 = 0.f, y3 = 0.f;
    float e0 = 0.f, e1 = 0.f, e2 = 0.f, e3 = 0.f;
    #pragma unroll
    for (int r = 0; r < 4; ++r) {
        const int t = tb - r;
        if ((unsigned)t > (unsigned)(TFR - 1)) continue;   // same mask for y and env
        const int n = nb + (r << 7);
        ushort4 v = *(const ushort4*)(fb + (size_t)t * NFFT + n);
        float4  wv = *(const float4*)(wnd + n);
        y0 += bf2f(v.x); e0 += wv.x * wv.x;
        y1 += bf2f(v.y); e1 += wv.y * wv.y;
        y2 += bf2f(v.z); e2 += wv.z * wv.z;
        y3 += bf2f(v.w); e3 += wv.w * wv.w;
    }
    float4 res = make_float4(y0 / e0, y1 / e1, y2 / e2, y3 / e3);
    *(float4*)(out + (size_t)bc * OUTLEN + o) = res;
}

// ---------------------------------------------------------------------------
extern "C" void kernel_launch(void* const* d_in, const int* in_sizes, int n_in,
                              void* d_out, int out_size, void* d_ws, size_t ws_size,
                              hipStream_t stream) {
    (void)in_sizes; (void)n_in; (void)out_size; (void)ws_size;
    const float* X   = (const float*)d_in[0];
    const float* wnd = (const float*)d_in[1];
    float* out = (float*)d_out;

    uint4* Wf = (uint4*)d_ws;                                            // 557 KB
    __hip_bfloat16* frames = (__hip_bfloat16*)((char*)d_ws + (1 << 20)); // 64 MB

    k_wgen<<<136, 256, 0, stream>>>(wnd, Wf);
    k_mm<<<1024, 256, 0, stream>>>(X, Wf, frames);
    k_ola<<<dim3((OUTLEN / 4 + 255) / 256, NBC), 256, 0, stream>>>(frames, wnd, out);
}

// Round 3
// 118.337 us; speedup vs baseline: 1.0475x; 1.0475x over previous
//
#include <hip/hip_runtime.h>
#include <hip/hip_bf16.h>

#define NFFT    512
#define HOPSZ   128
#define FBINS   257
#define TFR     2048
#define NBC     32            // B*C
#define KSTEPS  17            // 544 / 32
#define OUTLEN  262016        // (T-1)*HOP
#define SPAD    256           // n_fft/2 (center trim)

typedef __bf16 bf16x8 __attribute__((ext_vector_type(8)));
typedef float  f32x4  __attribute__((ext_vector_type(4)));

static __device__ __forceinline__ float bf2f(unsigned short u) {
    union { unsigned int i; float f; } x; x.i = (unsigned int)u << 16; return x.f;
}

__device__ __forceinline__ void gld_lds16(const void* g, void* l) {
    __builtin_amdgcn_global_load_lds(
        (const __attribute__((address_space(1))) unsigned int*)g,
        (__attribute__((address_space(3))) unsigned int*)l, 16, 0, 0);
}

// ---------------------------------------------------------------------------
// Kernel 1: W' in MFMA A-fragment order (verified in R2).
//   Wf[(ks*32 + rt)*64 + lane]: 8 bf16, elem j:
//     n = rt*16 + (lane&15),  k = ks*32 + 4*(lane>>4) + (j&3) + 16*(j>>2)
// ---------------------------------------------------------------------------
__global__ __launch_bounds__(256) void k_wgen(const float* __restrict__ wnd,
                                              uint4* __restrict__ Wf) {
    const int gid  = blockIdx.x * 256 + threadIdx.x;   // < 34816
    const int lane = gid & 63;
    const int rt   = (gid >> 6) & 31;
    const int ks   = gid >> 11;
    const int n    = rt * 16 + (lane & 15);
    const int kb   = ks * 32 + ((lane >> 4) << 2);
    const float wn = wnd[n] * (1.0f / 512.0f);
    union { uint4 u; unsigned short h[8]; } o;
    #pragma unroll
    for (int j = 0; j < 8; ++j) {
        const int k = kb + (j & 3) + 16 * (j >> 2);
        float val = 0.0f;
        if (k < 2 * FBINS) {
            const int f = k >> 1;
            const bool edge = (f == 0) || (f == 256);
            const float cf = edge ? 1.0f : 2.0f;
            const int m = (f * n) & (NFFT - 1);
            const float ang = (float)m * 0.01227184630308513f; // 2*pi/512
            float s, c;
            __sincosf(ang, &s, &c);
            val = (k & 1) ? (edge ? 0.0f : -cf * wn * s) : (cf * wn * c);
        }
        __hip_bfloat16 hb = __float2bfloat16(val);
        o.h[j] = *(unsigned short*)&hb;
    }
    Wf[gid] = o.u;
}

// ---------------------------------------------------------------------------
// Kernel 2: frames = W' @ X. BM=512 (full M, X read once), BN=64, BK=32.
//   256 thr (4 waves); wave w: rows [128w,+128) x all 64 t; acc[8][4].
//   2-phase dbuf: {loadB(regs,next); stageA(gload_lds,next); compute(cur);
//                  writeB(next); barrier}.  72 KB LDS -> 2 blocks/CU.
//   A & B both stored in LDS in fragment order -> ds_read_b128 conflict-free.
// ---------------------------------------------------------------------------
__global__ __launch_bounds__(256, 2) void k_mm(
    const float* __restrict__ X,
    const uint4* __restrict__ Wf,
    __hip_bfloat16* __restrict__ frames)
{
    __shared__ uint4 Albuf[2][2048];   // 2 x 32 KB
    __shared__ uint4 Bbuf[2][256];     // 2 x  4 KB

    const int tid  = threadIdx.x;
    const int lane = tid & 63;
    const int w    = tid >> 6;                 // row-group 0..3
    const int bc   = blockIdx.x >> 5;          // 1024 blocks = 32 bc x 32 panels
    const int t0   = (blockIdx.x & 31) << 6;
    const float2* __restrict__ X2 = (const float2*)X + (size_t)bc * FBINS * TFR;

    // B staging role: st_t = t-col (0..63), st_g = f-group (0..3)
    const int st_t = tid & 63;
    const int st_g = tid >> 6;
    const int q0 = (2 * st_g) & 3;             // frag quarter for k=8g..8g+3
    const int q1 = (2 * st_g + 1) & 3;         // frag quarter for k=8g+4..8g+7
    const int hf = st_g >> 1;                  // frag half (k<16 vs k>=16)
    const int tb = (st_t >> 4) * 64 + (st_t & 15);

    f32x4 acc[8][4] = {};
    float2 xv[4];

    auto loadB = [&](int ks) {                 // issue 4x 8B global loads
        #pragma unroll
        for (int d = 0; d < 4; ++d) {
            const int f = ks * 16 + 4 * st_g + d;
            xv[d] = (f < FBINS) ? X2[(size_t)f * TFR + t0 + st_t]
                                : make_float2(0.f, 0.f);
        }
    };
    auto stageA = [&](int ks, int bi) {        // 8x global_load_lds dwordx4
        const uint4* src = Wf + (size_t)ks * 2048;
        #pragma unroll
        for (int r = 0; r < 8; ++r)
            gld_lds16(src + r * 256 + tid, &Albuf[bi][r * 256 + tid]);
    };
    auto writeB = [&](int bi) {                // cvt + 2x ds_write_b64
        union { uint2 u; __hip_bfloat16 h[4]; } lo, hi;
        lo.h[0] = __float2bfloat16(xv[0].x); lo.h[1] = __float2bfloat16(xv[0].y);
        lo.h[2] = __float2bfloat16(xv[1].x); lo.h[3] = __float2bfloat16(xv[1].y);
        hi.h[0] = __float2bfloat16(xv[2].x); hi.h[1] = __float2bfloat16(xv[2].y);
        hi.h[2] = __float2bfloat16(xv[3].x); hi.h[3] = __float2bfloat16(xv[3].y);
        ((uint2*)&Bbuf[bi][tb + 16 * q0])[hf] = lo.u;
        ((uint2*)&Bbuf[bi][tb + 16 * q1])[hf] = hi.u;
    };
    auto compute = [&](int bi) {
        uint4 a[8], b[4];
        const uint4* Ab = &Albuf[bi][(w * 8) * 64 + lane];
        const uint4* Bb = &Bbuf[bi][lane];
        #pragma unroll
        for (int ni = 0; ni < 4; ++ni) b[ni] = Bb[ni * 64];
        #pragma unroll
        for (int mi = 0; mi < 8; ++mi) a[mi] = Ab[mi * 64];
        #pragma unroll
        for (int mi = 0; mi < 8; ++mi)
            #pragma unroll
            for (int ni = 0; ni < 4; ++ni)
                acc[mi][ni] = __builtin_amdgcn_mfma_f32_16x16x32_bf16(
                    __builtin_bit_cast(bf16x8, a[mi]),
                    __builtin_bit_cast(bf16x8, b[ni]), acc[mi][ni], 0, 0, 0);
    };

    loadB(0);
    stageA(0, 0);
    writeB(0);
    __syncthreads();
    int cur = 0;
    for (int ks = 0; ks < KSTEPS; ++ks) {
        const bool more = (ks + 1 < KSTEPS);
        if (more) { loadB(ks + 1); stageA(ks + 1, cur ^ 1); }
        compute(cur);
        if (more) writeB(cur ^ 1);
        __syncthreads();
        cur ^= 1;
    }

    // epilogue: C/D row=(l>>4)*4+reg -> n, col=l&15 -> t (verified R1/R2)
    const int rlo  = lane & 15;
    const int rrow = (lane >> 4) << 2;
    unsigned short* fb = (unsigned short*)frames;
    #pragma unroll
    for (int mi = 0; mi < 8; ++mi) {
        const int nbase = w * 128 + mi * 16 + rrow;
        #pragma unroll
        for (int ni = 0; ni < 4; ++ni) {
            const int t = t0 + ni * 16 + rlo;
            union { ushort4 u; __hip_bfloat16 h[4]; } pk;
            pk.h[0] = __float2bfloat16(acc[mi][ni][0]);
            pk.h[1] = __float2bfloat16(acc[mi][ni][1]);
            pk.h[2] = __float2bfloat16(acc[mi][ni][2]);
            pk.h[3] = __float2bfloat16(acc[mi][ni][3]);
            *(ushort4*)(fb + (((size_t)(bc * TFR + t)) << 9) + nbase) = pk.u;
        }
    }
}

// ---------------------------------------------------------------------------
// Kernel 3: overlap-add + envelope normalize. 4 outputs / thread.
// ---------------------------------------------------------------------------
__global__ __launch_bounds__(256) void k_ola(
    const __hip_bfloat16* __restrict__ frames,
    const float* __restrict__ wnd,
    float* __restrict__ out)
{
    const int bc = blockIdx.y;
    const int o  = (blockIdx.x * 256 + threadIdx.x) * 4;
    if (o >= OUTLEN) return;
    const int s   = o + SPAD;
    const int tb_ = s >> 7;
    const int nb  = s & (HOPSZ - 1);
    const unsigned short* fb = (const unsigned short*)frames + (size_t)bc * TFR * NFFT;
    float y0 = 0.f, y1 = 0.f, y2 = 0.f, y3 = 0.f;
    float e0 = 0.f, e1 = 0.f, e2 = 0.f, e3 = 0.f;
    #pragma unroll
    for (int r = 0; r < 4; ++r) {
        const int t = tb_ - r;
        if ((unsigned)t > (unsigned)(TFR - 1)) continue;
        const int n = nb + (r << 7);
        ushort4 v = *(const ushort4*)(fb + (size_t)t * NFFT + n);
        float4  wv = *(const float4*)(wnd + n);
        y0 += bf2f(v.x); e0 += wv.x * wv.x;
        y1 += bf2f(v.y); e1 += wv.y * wv.y;
        y2 += bf2f(v.z); e2 += wv.z * wv.z;
        y3 += bf2f(v.w); e3 += wv.w * wv.w;
    }
    float4 res = make_float4(y0 / e0, y1 / e1, y2 / e2, y3 / e3);
    *(float4*)(out + (size_t)bc * OUTLEN + o) = res;
}

// ---------------------------------------------------------------------------
extern "C" void kernel_launch(void* const* d_in, const int* in_sizes, int n_in,
                              void* d_out, int out_size, void* d_ws, size_t ws_size,
                              hipStream_t stream) {
    (void)in_sizes; (void)n_in; (void)out_size; (void)ws_size;
    const float* X   = (const float*)d_in[0];
    const float* wnd = (const float*)d_in[1];
    float* out = (float*)d_out;

    uint4* Wf = (uint4*)d_ws;                                            // 544 KB
    __hip_bfloat16* frames = (__hip_bfloat16*)((char*)d_ws + (1 << 20)); // 64 MB

    k_wgen<<<136, 256, 0, stream>>>(wnd, Wf);
    k_mm<<<1024, 256, 0, stream>>>(X, Wf, frames);
    k_ola<<<dim3((OUTLEN / 4 + 255) / 256, NBC), 256, 0, stream>>>(frames, wnd, out);
}